// Round 1
// baseline (12656.052 us; speedup 1.0000x reference)
//
#include <hip/hip_runtime.h>
#include <stdint.h>
#include <math.h>

// Problem constants (B, H, T) = (16, 2048, 512)
#define Hdim   2048
#define Bdim   16
#define Tsteps 512
#define NWG    128   // workgroups; each owns KC columns of h
#define TPB    256   // 4 waves
#define KC     16    // h-columns per WG  (NWG*KC == Hdim)
#define NCHUNK 16    // K-chunks of 32 per wave (wave K-range = 512)

typedef __attribute__((ext_vector_type(8))) short short8_t;  // 8 bf16 (4 VGPRs)
typedef __attribute__((ext_vector_type(4))) float f32x4;     // MFMA C/D

__device__ __forceinline__ short f2bf(float x) {
  uint32_t u = __builtin_bit_cast(uint32_t, x);
  u += 0x7fffu + ((u >> 16) & 1u);   // RNE
  return (short)(u >> 16);
}

__device__ __forceinline__ short8_t load8_bf(const float* __restrict__ p) {
  short8_t r;
#pragma unroll
  for (int j = 0; j < 8; ++j) r[j] = f2bf(p[j]);
  return r;
}

// Grid-wide barrier: monotonic epoch, no counter reset needed.
// cnt at ws[0], epoch at ws+256B (separate cache lines).
__device__ __forceinline__ void gbar(uint32_t* cnt, uint32_t* epoch, uint32_t n) {
  __threadfence();            // release: drain vmem, write back L2 (cross-XCD)
  __syncthreads();
  if (threadIdx.x == 0) {
    uint32_t a = __hip_atomic_fetch_add(cnt, 1u, __ATOMIC_ACQ_REL, __HIP_MEMORY_SCOPE_AGENT);
    if (a == (uint32_t)NWG * n - 1u) {
      __hip_atomic_store(epoch, n, __ATOMIC_RELEASE, __HIP_MEMORY_SCOPE_AGENT);
    } else {
      while (__hip_atomic_load(epoch, __ATOMIC_RELAXED, __HIP_MEMORY_SCOPE_AGENT) < n) {
        __builtin_amdgcn_s_sleep(2);
      }
    }
  }
  __syncthreads();
  __threadfence();            // acquire: invalidate stale L1/L2 lines
}

__global__ void __launch_bounds__(TPB, 1) traj_kernel(
    const float* __restrict__ traj_z, const float* __restrict__ traj_input,
    const float* __restrict__ w_ih, const float* __restrict__ b_ih,
    const float* __restrict__ w_hh, const float* __restrict__ b_hh,
    const float* __restrict__ w_traj, const float* __restrict__ b_traj,
    float* __restrict__ out, uint16_t* __restrict__ hbuf, uint32_t* __restrict__ bar)
{
  const int tid  = threadIdx.x;
  const int wg   = blockIdx.x;
  const int wave = tid >> 6;
  const int lane = tid & 63;
  const int ln16 = lane & 15;       // MFMA: A row (batch) / B col (our 16 rows) / D col
  const int quad = lane >> 4;
  const int colbase = wg * KC;
  const int kwave   = wave * (Hdim / 4);   // this wave's K-quarter

  __shared__ float s_red[4][3][16][16];  // wave, gate-tile, m(batch), n(col)  = 12 KB
  __shared__ float s_x3[4][16];          // per-wave partial dot(h, w_traj) per batch
  __shared__ float s_x[16];              // running x per batch (identical in all WGs)

  // ---- preload w_hh slice as register-resident bf16 B-fragments ----
  // B[k][n]: n = lane&15 (row within tile), k = quad*8 + j within each 32-chunk.
  short8_t wf0[NCHUNK], wf1[NCHUNK], wf2[NCHUNK], wt[NCHUNK];
#pragma unroll
  for (int c = 0; c < NCHUNK; ++c) {
    const int k0 = kwave + c * 32 + quad * 8;
    wf0[c] = load8_bf(w_hh + (size_t)(0 * Hdim + colbase + ln16) * Hdim + k0); // r rows
    wf1[c] = load8_bf(w_hh + (size_t)(1 * Hdim + colbase + ln16) * Hdim + k0); // z rows
    wf2[c] = load8_bf(w_hh + (size_t)(2 * Hdim + colbase + ln16) * Hdim + k0); // n rows
    short8_t g = {0, 0, 0, 0, 0, 0, 0, 0};
    if (ln16 == 0) g = load8_bf(w_traj + k0);    // 4th tile: single w_traj row
    wt[c] = g;
  }

  // ---- per-thread epilogue constants: thread (eb, ekc) owns h[eb][colbase+ekc] ----
  const int eb   = tid >> 4;       // batch 0..15
  const int ekc  = tid & 15;       // col within WG slice
  const int ecol = colbase + ekc;
  const float wr = w_ih[ecol], wz = w_ih[Hdim + ecol], wn = w_ih[2 * Hdim + ecol];
  const float br = b_ih[ecol] + b_hh[ecol];                    // merged r biases
  const float bz = b_ih[Hdim + ecol] + b_hh[Hdim + ecol];      // merged z biases
  const float bin = b_ih[2 * Hdim + ecol];
  const float bhn = b_hh[2 * Hdim + ecol];                     // inside r*(...)
  const float bt  = b_traj[0];
  float h_own = traj_z[eb * Hdim + ecol];                      // fp32 own state

  if (tid < 16) s_x[tid] = traj_input[tid * Tsteps];           // x0 = traj_input[:,0]
  hbuf[0 * (Bdim * Hdim) + eb * Hdim + ecol] = (uint16_t)f2bf(h_own);

  uint32_t bcnt = 1;
  gbar(bar, bar + 64, bcnt);        // h_0 visible everywhere

  // step i: reads h_i, produces h_{i+1}; also dot(h_i, w_traj) -> x_i (i>=1).
  // out[:, i-1] = x_i. Extra iteration i==Tsteps computes only x_T -> out[:,T-1].
  for (int i = 0; i <= Tsteps; ++i) {
    const uint16_t* hb   = hbuf + (i & 1) * (Bdim * Hdim);
    const uint16_t* hrow = hb + ln16 * Hdim + kwave + quad * 8;

    short8_t af[NCHUNK];
#pragma unroll
    for (int c = 0; c < NCHUNK; ++c)
      af[c] = *((const short8_t*)(hrow + c * 32));   // A[m=lane&15][k=quad*8+j]

    f32x4 a0 = {0.f, 0.f, 0.f, 0.f}, a1 = a0, a2 = a0, a3 = a0;
#pragma unroll
    for (int c = 0; c < NCHUNK; ++c) {
      a0 = __builtin_amdgcn_mfma_f32_16x16x32_bf16(af[c], wf0[c], a0, 0, 0, 0);
      a1 = __builtin_amdgcn_mfma_f32_16x16x32_bf16(af[c], wf1[c], a1, 0, 0, 0);
      a2 = __builtin_amdgcn_mfma_f32_16x16x32_bf16(af[c], wf2[c], a2, 0, 0, 0);
      a3 = __builtin_amdgcn_mfma_f32_16x16x32_bf16(af[c], wt[c],  a3, 0, 0, 0);
    }

    // D[m][n]: n = lane&15, m = quad*4 + r
#pragma unroll
    for (int r = 0; r < 4; ++r) {
      const int m = quad * 4 + r;
      s_red[wave][0][m][ln16] = a0[r];
      s_red[wave][1][m][ln16] = a1[r];
      s_red[wave][2][m][ln16] = a2[r];
    }
    if (ln16 == 0) {
#pragma unroll
      for (int r = 0; r < 4; ++r) s_x3[wave][quad * 4 + r] = a3[r];
    }
    __syncthreads();

    if (tid < 16 && i > 0) {   // x_i = x_{i-1} + dot(h_i, w_traj) + b_traj
      const float xd = s_x3[0][tid] + s_x3[1][tid] + s_x3[2][tid] + s_x3[3][tid];
      s_x[tid] += xd + bt;
    }
    __syncthreads();

    if (wg == 0 && tid < 16 && i > 0) out[tid * Tsteps + (i - 1)] = s_x[tid];
    if (i == Tsteps) break;

    // gates for (eb, ecol)
    const float gr = s_red[0][0][eb][ekc] + s_red[1][0][eb][ekc] + s_red[2][0][eb][ekc] + s_red[3][0][eb][ekc];
    const float gz = s_red[0][1][eb][ekc] + s_red[1][1][eb][ekc] + s_red[2][1][eb][ekc] + s_red[3][1][eb][ekc];
    const float gn = s_red[0][2][eb][ekc] + s_red[1][2][eb][ekc] + s_red[2][2][eb][ekc] + s_red[3][2][eb][ekc];
    const float x  = s_x[eb];
    const float rr = 1.f / (1.f + expf(-(x * wr + br + gr)));
    const float zz = 1.f / (1.f + expf(-(x * wz + bz + gz)));
    const float nn = tanhf(x * wn + bin + rr * (gn + bhn));
    h_own = (1.f - zz) * nn + zz * h_own;

    hbuf[((i + 1) & 1) * (Bdim * Hdim) + eb * Hdim + ecol] = (uint16_t)f2bf(h_own);

    ++bcnt;
    gbar(bar, bar + 64, bcnt);      // h_{i+1} visible; also protects double-buffer reuse
  }
}

extern "C" void kernel_launch(void* const* d_in, const int* in_sizes, int n_in,
                              void* d_out, int out_size, void* d_ws, size_t ws_size,
                              hipStream_t stream) {
  const float* traj_z     = (const float*)d_in[0];
  const float* traj_input = (const float*)d_in[1];
  const float* w_ih   = (const float*)d_in[2];
  const float* b_ih   = (const float*)d_in[3];
  const float* w_hh   = (const float*)d_in[4];
  const float* b_hh   = (const float*)d_in[5];
  const float* w_traj = (const float*)d_in[6];
  const float* b_traj = (const float*)d_in[7];
  float* out = (float*)d_out;

  uint8_t*  ws   = (uint8_t*)d_ws;
  uint32_t* bar  = (uint32_t*)ws;              // cnt @0, epoch @+256B; 512B region
  uint16_t* hbuf = (uint16_t*)(ws + 512);      // 2 * 16 * 2048 bf16 = 128 KB

  (void)hipMemsetAsync(bar, 0, 512, stream);   // barrier state must start at 0
  hipLaunchKernelGGL(traj_kernel, dim3(NWG), dim3(TPB), 0, stream,
                     traj_z, traj_input, w_ih, b_ih, w_hh, b_hh, w_traj, b_traj,
                     out, hbuf, bar);
}

// Round 2
// 2984.550 us; speedup vs baseline: 4.2405x; 4.2405x over previous
//
#include <hip/hip_runtime.h>
#include <stdint.h>
#include <math.h>

// Problem constants (B, H, T) = (16, 2048, 512)
#define Hdim   2048
#define Bdim   16
#define Tsteps 512
#define NWG    128   // workgroups; each owns KC columns of h
#define TPB    256   // 4 waves
#define KC     16    // h-columns per WG  (NWG*KC == Hdim)
#define NCHUNK 16    // K-chunks of 32 per wave (wave K-range = 512)
#define FLAGSTRIDE 32  // uint32s between per-WG flags (128B)

typedef __attribute__((ext_vector_type(8))) short short8_t;  // 8 bf16 (4 VGPRs)
typedef __attribute__((ext_vector_type(4))) float f32x4;     // MFMA C/D

__device__ __forceinline__ short f2bf(float x) {
  uint32_t u = __builtin_bit_cast(uint32_t, x);
  u += 0x7fffu + ((u >> 16) & 1u);   // RNE
  return (short)(u >> 16);
}

__device__ __forceinline__ short8_t load8_bf(const float* __restrict__ p) {
  short8_t r;
#pragma unroll
  for (int j = 0; j < 8; ++j) r[j] = f2bf(p[j]);
  return r;
}

// ---- flag barrier helpers (no fences, no RMW atomics) ----
// publish: all waves' agent-scope h-stores are drained by the s_waitcnt vmcnt(0)
// that __syncthreads() emits; then one thread stores this WG's arrival flag.
__device__ __forceinline__ void publish(uint32_t* flags, int wg, int tid, uint32_t n) {
  __syncthreads();
  if (tid == 0)
    __hip_atomic_store(flags + wg * FLAGSTRIDE, n, __ATOMIC_RELAXED, __HIP_MEMORY_SCOPE_AGENT);
}
// waitall: thread t (<NWG) polls WG t's flag until it reaches n.
__device__ __forceinline__ void waitall(const uint32_t* flags, int tid, uint32_t n) {
  if (tid < NWG) {
    while (__hip_atomic_load(flags + tid * FLAGSTRIDE, __ATOMIC_RELAXED,
                             __HIP_MEMORY_SCOPE_AGENT) < n) {
      __builtin_amdgcn_s_sleep(1);
    }
  }
  __syncthreads();
}

__global__ void __launch_bounds__(TPB, 1) traj_kernel(
    const float* __restrict__ traj_z, const float* __restrict__ traj_input,
    const float* __restrict__ w_ih, const float* __restrict__ b_ih,
    const float* __restrict__ w_hh, const float* __restrict__ b_hh,
    const float* __restrict__ w_traj, const float* __restrict__ b_traj,
    float* __restrict__ out, uint32_t* __restrict__ hbuf32, uint32_t* __restrict__ flags)
{
  const int tid  = threadIdx.x;
  const int wg   = blockIdx.x;
  const int wave = tid >> 6;
  const int lane = tid & 63;
  const int ln16 = lane & 15;       // MFMA: A row (batch) / B col (our 16 rows) / D col
  const int quad = lane >> 4;
  const int colbase = wg * KC;
  const int kwave   = wave * (Hdim / 4);   // this wave's K-quarter

  uint64_t* hbuf64 = (uint64_t*)hbuf32;

  __shared__ float s_red[4][3][16][16];  // wave, gate-tile, m(batch), n(col)  = 12 KB
  __shared__ float s_x3[4][16];          // per-wave partial dot(h, w_traj) per batch
  __shared__ float s_x[16];              // running x per batch (identical in all WGs)

  // ---- preload w_hh slice as register-resident bf16 B-fragments ----
  // B[k][n]: n = lane&15 (row within tile), k = quad*8 + j within each 32-chunk.
  short8_t wf0[NCHUNK], wf1[NCHUNK], wf2[NCHUNK], wt[NCHUNK];
#pragma unroll
  for (int c = 0; c < NCHUNK; ++c) {
    const int k0 = kwave + c * 32 + quad * 8;
    wf0[c] = load8_bf(w_hh + (size_t)(0 * Hdim + colbase + ln16) * Hdim + k0); // r rows
    wf1[c] = load8_bf(w_hh + (size_t)(1 * Hdim + colbase + ln16) * Hdim + k0); // z rows
    wf2[c] = load8_bf(w_hh + (size_t)(2 * Hdim + colbase + ln16) * Hdim + k0); // n rows
    short8_t g = {0, 0, 0, 0, 0, 0, 0, 0};
    if (ln16 == 0) g = load8_bf(w_traj + k0);    // 4th tile: single w_traj row
    wt[c] = g;
  }

  // ---- per-thread epilogue constants: thread (eb, ekc) owns h[eb][colbase+ekc] ----
  const int eb   = tid >> 4;       // batch 0..15
  const int ekc  = tid & 15;       // col within WG slice
  const int ecol = colbase + ekc;
  const float wr = w_ih[ecol], wz = w_ih[Hdim + ecol], wn = w_ih[2 * Hdim + ecol];
  const float br = b_ih[ecol] + b_hh[ecol];                    // merged r biases
  const float bz = b_ih[Hdim + ecol] + b_hh[Hdim + ecol];      // merged z biases
  const float bin = b_ih[2 * Hdim + ecol];
  const float bhn = b_hh[2 * Hdim + ecol];                     // inside r*(...)
  const float bt  = b_traj[0];
  float h_own = traj_z[eb * Hdim + ecol];                      // fp32 own state

  if (tid < 16) s_x[tid] = traj_input[tid * Tsteps];           // x0 = traj_input[:,0]

  // ---- publish h_0 (agent-scope writethrough stores; pack 2 bf16 per dword) ----
  {
    uint32_t mybits = (uint32_t)(uint16_t)f2bf(h_own);
    uint32_t nb = (uint32_t)__shfl_xor((int)mybits, 1, 64);
    if ((tid & 1) == 0) {
      uint32_t packed = (mybits & 0xffffu) | (nb << 16);
      __hip_atomic_store(hbuf32 + 0 * (Bdim * Hdim / 2) + ((eb * Hdim + ecol) >> 1),
                         packed, __ATOMIC_RELAXED, __HIP_MEMORY_SCOPE_AGENT);
    }
  }
  publish(flags, wg, tid, 1);

  // step i: reads h_i, produces h_{i+1}; also dot(h_i, w_traj) -> x_i (i>=1).
  // out[:, i-1] = x_i. Extra iteration i==Tsteps computes only x_T -> out[:,T-1].
  for (int i = 0; i <= Tsteps; ++i) {
    waitall(flags, tid, (uint32_t)(i + 1));   // all WGs have published h_i

    // A-fragments of h_i via agent-scope loads (bypass stale per-XCD L2)
    const uint64_t* hrow = hbuf64 + (size_t)(i & 1) * (Bdim * Hdim / 4)
                         + ((ln16 * Hdim + kwave + quad * 8) >> 2);
    short8_t af[NCHUNK];
#pragma unroll
    for (int c = 0; c < NCHUNK; ++c) {
      union { uint64_t u[2]; short8_t s; } cv;
      cv.u[0] = __hip_atomic_load(hrow + c * 8,     __ATOMIC_RELAXED, __HIP_MEMORY_SCOPE_AGENT);
      cv.u[1] = __hip_atomic_load(hrow + c * 8 + 1, __ATOMIC_RELAXED, __HIP_MEMORY_SCOPE_AGENT);
      af[c] = cv.s;
    }

    f32x4 a0 = {0.f, 0.f, 0.f, 0.f}, a1 = a0, a2 = a0, a3 = a0;
#pragma unroll
    for (int c = 0; c < NCHUNK; ++c) {
      a0 = __builtin_amdgcn_mfma_f32_16x16x32_bf16(af[c], wf0[c], a0, 0, 0, 0);
      a1 = __builtin_amdgcn_mfma_f32_16x16x32_bf16(af[c], wf1[c], a1, 0, 0, 0);
      a2 = __builtin_amdgcn_mfma_f32_16x16x32_bf16(af[c], wf2[c], a2, 0, 0, 0);
      a3 = __builtin_amdgcn_mfma_f32_16x16x32_bf16(af[c], wt[c],  a3, 0, 0, 0);
    }

    // D[m][n]: n = lane&15, m = quad*4 + r
#pragma unroll
    for (int r = 0; r < 4; ++r) {
      const int m = quad * 4 + r;
      s_red[wave][0][m][ln16] = a0[r];
      s_red[wave][1][m][ln16] = a1[r];
      s_red[wave][2][m][ln16] = a2[r];
    }
    if (ln16 == 0) {
#pragma unroll
      for (int r = 0; r < 4; ++r) s_x3[wave][quad * 4 + r] = a3[r];
    }
    __syncthreads();

    if (tid < 16 && i > 0) {   // x_i = x_{i-1} + dot(h_i, w_traj) + b_traj
      const float xd = s_x3[0][tid] + s_x3[1][tid] + s_x3[2][tid] + s_x3[3][tid];
      s_x[tid] += xd + bt;
    }
    __syncthreads();

    if (wg == 0 && tid < 16 && i > 0) out[tid * Tsteps + (i - 1)] = s_x[tid];
    if (i == Tsteps) break;

    // gates for (eb, ecol)
    const float gr = s_red[0][0][eb][ekc] + s_red[1][0][eb][ekc] + s_red[2][0][eb][ekc] + s_red[3][0][eb][ekc];
    const float gz = s_red[0][1][eb][ekc] + s_red[1][1][eb][ekc] + s_red[2][1][eb][ekc] + s_red[3][1][eb][ekc];
    const float gn = s_red[0][2][eb][ekc] + s_red[1][2][eb][ekc] + s_red[2][2][eb][ekc] + s_red[3][2][eb][ekc];
    const float x  = s_x[eb];
    const float rr = 1.f / (1.f + expf(-(x * wr + br + gr)));
    const float zz = 1.f / (1.f + expf(-(x * wz + bz + gz)));
    const float nn = tanhf(x * wn + bin + rr * (gn + bhn));
    h_own = (1.f - zz) * nn + zz * h_own;

    // publish h_{i+1}
    {
      uint32_t mybits = (uint32_t)(uint16_t)f2bf(h_own);
      uint32_t nb = (uint32_t)__shfl_xor((int)mybits, 1, 64);
      if ((tid & 1) == 0) {
        uint32_t packed = (mybits & 0xffffu) | (nb << 16);
        __hip_atomic_store(hbuf32 + (size_t)((i + 1) & 1) * (Bdim * Hdim / 2)
                           + ((eb * Hdim + ecol) >> 1),
                           packed, __ATOMIC_RELAXED, __HIP_MEMORY_SCOPE_AGENT);
      }
    }
    publish(flags, wg, tid, (uint32_t)(i + 2));
  }
}

extern "C" void kernel_launch(void* const* d_in, const int* in_sizes, int n_in,
                              void* d_out, int out_size, void* d_ws, size_t ws_size,
                              hipStream_t stream) {
  const float* traj_z     = (const float*)d_in[0];
  const float* traj_input = (const float*)d_in[1];
  const float* w_ih   = (const float*)d_in[2];
  const float* b_ih   = (const float*)d_in[3];
  const float* w_hh   = (const float*)d_in[4];
  const float* b_hh   = (const float*)d_in[5];
  const float* w_traj = (const float*)d_in[6];
  const float* b_traj = (const float*)d_in[7];
  float* out = (float*)d_out;

  uint8_t*  ws    = (uint8_t*)d_ws;
  uint32_t* flags = (uint32_t*)ws;                 // NWG*FLAGSTRIDE u32 = 16 KB
  uint32_t* hbuf  = (uint32_t*)(ws + NWG * FLAGSTRIDE * 4);  // 2*16*2048 bf16 = 128 KB

  (void)hipMemsetAsync(flags, 0, NWG * FLAGSTRIDE * 4, stream);
  hipLaunchKernelGGL(traj_kernel, dim3(NWG), dim3(TPB), 0, stream,
                     traj_z, traj_input, w_ih, b_ih, w_hh, b_hh, w_traj, b_traj,
                     out, hbuf, flags);
}